// Round 5
// baseline (209.824 us; speedup 1.0000x reference)
//
#include <hip/hip_runtime.h>
#include <math.h>

#define NATOMS 128
#define NALIGN 64

// K1: 16 frames/block, 16 lanes per frame, 8 atoms per lane
#define TPB1   256
#define FPB1   16
// K2: pure streaming apply, 16 threads/frame, 8 atoms per thread
#define TPB2   256

// Branchless Jacobi rotation on symmetric 3x3 for pair (p,q); third index r.
// Tiny/zero apq degenerates to identity rotation via clamped denominator
// (tau -> +-huge -> t -> 0, c -> 1, s -> 0). NaN-free, divergence-free.
#define JACOBI_ROT(app, aqq, apq, arp, arq, pcol, qcol)                 \
  {                                                                     \
    float _apq = (apq);                                                 \
    float _den = 2.0f * _apq;                                           \
    _den = copysignf(fmaxf(fabsf(_den), 1e-30f), _den);                 \
    float _tau = ((aqq) - (app)) / _den;                                \
    float _t = (_tau >= 0.0f ? 1.0f : -1.0f) /                          \
               (fabsf(_tau) + sqrtf(1.0f + _tau * _tau));               \
    float _c = rsqrtf(1.0f + _t * _t);                                  \
    float _s = _t * _c;                                                 \
    (app) -= _t * _apq;                                                 \
    (aqq) += _t * _apq;                                                 \
    (apq) = 0.0f;                                                       \
    float _rp = (arp), _rq = (arq);                                     \
    (arp) = _c * _rp - _s * _rq;                                        \
    (arq) = _s * _rp + _c * _rq;                                        \
    _Pragma("unroll")                                                   \
    for (int _r = 0; _r < 3; _r++) {                                    \
      float _vp = v[3 * _r + (pcol)], _vq = v[3 * _r + (qcol)];         \
      v[3 * _r + (pcol)] = _c * _vp - _s * _vq;                         \
      v[3 * _r + (qcol)] = _s * _vp + _c * _vq;                         \
    }                                                                   \
  }

// SVD of 3x3 m[9] (row-major) -> R(9). Branchless throughout.
__device__ __forceinline__ void svd_rotation(const float* m, float* R)
{
    // A = M^T M (symmetric)
    float a00 = m[0]*m[0] + m[3]*m[3] + m[6]*m[6];
    float a01 = m[0]*m[1] + m[3]*m[4] + m[6]*m[7];
    float a02 = m[0]*m[2] + m[3]*m[5] + m[6]*m[8];
    float a11 = m[1]*m[1] + m[4]*m[4] + m[7]*m[7];
    float a12 = m[1]*m[2] + m[4]*m[5] + m[7]*m[8];
    float a22 = m[2]*m[2] + m[5]*m[5] + m[8]*m[8];

    float v[9] = {1.f,0.f,0.f, 0.f,1.f,0.f, 0.f,0.f,1.f};
    #pragma unroll
    for (int sweep = 0; sweep < 5; sweep++) {
        JACOBI_ROT(a00, a11, a01, a02, a12, 0, 1);
        JACOBI_ROT(a00, a22, a02, a01, a12, 0, 2);
        JACOBI_ROT(a11, a22, a12, a01, a02, 1, 2);
    }

    // sort eigenvalues descending, permuting V columns (branchless)
    float dd[3] = {a00, a11, a22};
    #pragma unroll
    for (int pass = 0; pass < 3; pass++) {
        const int ii = (pass == 2) ? 1 : 0;   // 0,0,1
        const int jj = (pass == 0) ? 1 : 2;   // 1,2,2
        float di = dd[ii], dj = dd[jj];
        bool sw = di < dj;
        dd[ii] = sw ? dj : di;
        dd[jj] = sw ? di : dj;
        #pragma unroll
        for (int rr = 0; rr < 3; rr++) {
            float a = v[3*rr+ii], b = v[3*rr+jj];
            v[3*rr+ii] = sw ? b : a;
            v[3*rr+jj] = sw ? a : b;
        }
    }

    float v0x = v[0], v0y = v[3], v0z = v[6];
    float v1x = v[1], v1y = v[4], v1z = v[7];
    float v2x = v[2], v2y = v[5], v2z = v[8];

    // u1 = normalize(M v0)
    float u1x = m[0]*v0x + m[1]*v0y + m[2]*v0z;
    float u1y = m[3]*v0x + m[4]*v0y + m[5]*v0z;
    float u1z = m[6]*v0x + m[7]*v0y + m[8]*v0z;
    float n1 = rsqrtf(fmaxf(u1x*u1x + u1y*u1y + u1z*u1z, 1e-30f));
    u1x *= n1; u1y *= n1; u1z *= n1;

    // u2 = normalize(M v1 - (u1 . M v1) u1)
    float u2x = m[0]*v1x + m[1]*v1y + m[2]*v1z;
    float u2y = m[3]*v1x + m[4]*v1y + m[5]*v1z;
    float u2z = m[6]*v1x + m[7]*v1y + m[8]*v1z;
    float d12 = u1x*u2x + u1y*u2y + u1z*u2z;
    u2x -= d12 * u1x; u2y -= d12 * u1y; u2z -= d12 * u1z;
    float n2 = rsqrtf(fmaxf(u2x*u2x + u2y*u2y + u2z*u2z, 1e-30f));
    u2x *= n2; u2y *= n2; u2z *= n2;

    // u3 = (u1 x u2) * sign(det V)
    float u3x = u1y*u2z - u1z*u2y;
    float u3y = u1z*u2x - u1x*u2z;
    float u3z = u1x*u2y - u1y*u2x;
    float cxv = v1y*v2z - v1z*v2y;
    float cyv = v1z*v2x - v1x*v2z;
    float czv = v1x*v2y - v1y*v2x;
    float detv = v0x*cxv + v0y*cyv + v0z*czv;
    float sg = (detv >= 0.f) ? 1.f : -1.f;
    u3x *= sg; u3y *= sg; u3z *= sg;

    // R[a][b] = u1[a]*v0[b] + u2[a]*v1[b] + u3[a]*v2[b]  (row-major)
    R[0] = u1x*v0x + u2x*v1x + u3x*v2x;
    R[1] = u1x*v0y + u2x*v1y + u3x*v2y;
    R[2] = u1x*v0z + u2x*v1z + u3x*v2z;
    R[3] = u1y*v0x + u2y*v1x + u3y*v2x;
    R[4] = u1y*v0y + u2y*v1y + u3y*v2y;
    R[5] = u1y*v0z + u2y*v1z + u3y*v2z;
    R[6] = u1z*v0x + u2z*v1x + u3z*v2x;
    R[7] = u1z*v0y + u2z*v1y + u3z*v2y;
    R[8] = u1z*v0z + u2z*v1z + u3z*v2z;
}

// ============ K1: streaming covariance + lane-dense SVD -> rmat[B][12] ======
// After the single barrier, waves 1..3 exit immediately (no stage 3), so
// blocks self-stagger on the CU instead of convoying.
__global__ __launch_bounds__(TPB1) void cov_svd_kernel(
    const float* __restrict__ traj,
    const float* __restrict__ ref_pos,
    const int* __restrict__ align_idx,
    float* __restrict__ rmat,
    int B)
{
    // rmap: per atom a, (centered ref xyz, weight). Swizzled slot
    // ((a&7)<<4)|(a>>3): lane sub's 8 reads (atoms 8sub..8sub+7) become
    // stride-16B ds_read_b128 (2-way aliasing, free); the four 16-lane
    // groups of a wave read identical addresses (broadcast).
    __shared__ float4 s_rmap[NATOMS];
    __shared__ float  s_cov[FPB1][13];   // stride 13: conflict-free lane-major

    const int t   = threadIdx.x;
    const int f   = t >> 4;              // local frame 0..15
    const int sub = t & 15;              // 8-atom chunk within frame
    const int gf  = blockIdx.x * FPB1 + f;
    const bool valid = (gf < B);

    // ---- issue the coalesced traj read first: 8 atoms = 6 float4 ----
    float x[8], y[8], z[8];
    if (valid) {
        const float4* p = (const float4*)(traj + (size_t)gf * (NATOMS * 3) + sub * 24);
        float4 q0 = p[0], q1 = p[1], q2 = p[2], q3 = p[3], q4 = p[4], q5 = p[5];
        x[0]=q0.x; y[0]=q0.y; z[0]=q0.z;
        x[1]=q0.w; y[1]=q1.x; z[1]=q1.y;
        x[2]=q1.z; y[2]=q1.w; z[2]=q2.x;
        x[3]=q2.y; y[3]=q2.z; z[3]=q2.w;
        x[4]=q3.x; y[4]=q3.y; z[4]=q3.z;
        x[5]=q3.w; y[5]=q4.x; z[5]=q4.y;
        x[6]=q4.z; y[6]=q4.w; z[6]=q5.x;
        x[7]=q5.y; y[7]=q5.z; z[7]=q5.w;
    } else {
        #pragma unroll
        for (int j = 0; j < 8; j++) { x[j]=0.f; y[j]=0.f; z[j]=0.f; }
    }

    // ---- wave 0: build centered-ref inverse map ----
    if (t < NALIGN) {
        const float4 z4 = make_float4(0.f, 0.f, 0.f, 0.f);
        s_rmap[t]          = z4;   // same-wave DS program order: scatter below
        s_rmap[t + NALIGN] = z4;   // lands after these zeros

        int idx = align_idx[t];
        float rx = ref_pos[idx * 3 + 0];
        float ry = ref_pos[idx * 3 + 1];
        float rz = ref_pos[idx * 3 + 2];
        float sx = rx, sy = ry, sz = rz;
        #pragma unroll
        for (int off = 32; off >= 1; off >>= 1) {
            sx += __shfl_xor(sx, off);
            sy += __shfl_xor(sy, off);
            sz += __shfl_xor(sz, off);
        }
        const float inv = 1.0f / (float)NALIGN;
        int slot = ((idx & 7) << 4) | (idx >> 3);
        s_rmap[slot] = make_float4(rx - sx * inv, ry - sy * inv, rz - sz * inv, 1.0f);
    }
    __syncthreads();

    // ---- fused centroid + cross-covariance (sum(r)=0 trick) ----
    {
        float sx = 0.f, sy = 0.f, sz = 0.f;
        float c[9] = {0.f,0.f,0.f,0.f,0.f,0.f,0.f,0.f,0.f};
        #pragma unroll
        for (int j = 0; j < 8; j++) {
            float4 rm = s_rmap[(j << 4) | sub];
            sx += rm.w * x[j]; sy += rm.w * y[j]; sz += rm.w * z[j];
            c[0] += x[j]*rm.x; c[1] += x[j]*rm.y; c[2] += x[j]*rm.z;
            c[3] += y[j]*rm.x; c[4] += y[j]*rm.y; c[5] += y[j]*rm.z;
            c[6] += z[j]*rm.x; c[7] += z[j]*rm.y; c[8] += z[j]*rm.z;
        }
        #pragma unroll
        for (int off = 8; off >= 1; off >>= 1) {
            sx += __shfl_xor(sx, off);
            sy += __shfl_xor(sy, off);
            sz += __shfl_xor(sz, off);
            #pragma unroll
            for (int jj = 0; jj < 9; jj++) c[jj] += __shfl_xor(c[jj], off);
        }
        if (sub == 0) {
            #pragma unroll
            for (int jj = 0; jj < 9; jj++) s_cov[f][jj] = c[jj];
            const float inv = 1.0f / (float)NALIGN;
            s_cov[f][9]  = sx * inv;
            s_cov[f][10] = sy * inv;
            s_cov[f][11] = sz * inv;
        }
    }
    __syncthreads();   // waves 1..3 exit right after this

    // ---- 16 lane-dense SVDs on a quarter of wave 0 ----
    if (t < FPB1) {
        int g = blockIdx.x * FPB1 + t;
        if (g < B) {
            float m[9];
            #pragma unroll
            for (int j = 0; j < 9; j++) m[j] = s_cov[t][j];
            float R[9];
            svd_rotation(m, R);
            float4* dst = (float4*)(rmat + (size_t)g * 12);
            dst[0] = make_float4(R[0], R[1], R[2], R[3]);
            dst[1] = make_float4(R[4], R[5], R[6], R[7]);
            dst[2] = make_float4(R[8], s_cov[t][9], s_cov[t][10], s_cov[t][11]);
        }
    }
}

// ============ K2: pure streaming apply (fill-shaped: no LDS/barrier) =======
__global__ __launch_bounds__(TPB2) void apply_kernel(
    const float* __restrict__ traj,
    const float* __restrict__ rmat,
    float* __restrict__ out,
    int B)
{
    const int gidx = blockIdx.x * TPB2 + threadIdx.x;
    const int f    = gidx >> 4;          // frame
    const int sub  = gidx & 15;          // 8-atom chunk
    if (f >= B) return;

    const float4* p = (const float4*)(traj + (size_t)f * (NATOMS * 3) + sub * 24);
    float4 q0 = p[0], q1 = p[1], q2 = p[2], q3 = p[3], q4 = p[4], q5 = p[5];

    const float4* Rt = (const float4*)(rmat + (size_t)f * 12);  // broadcast
    float4 Ra = Rt[0], Rb = Rt[1], Rc = Rt[2];
    float R0 = Ra.x, R1 = Ra.y, R2 = Ra.z, R3 = Ra.w;
    float R4 = Rb.x, R5 = Rb.y, R6 = Rb.z, R7 = Rb.w;
    float R8 = Rc.x, xcx = Rc.y, xcy = Rc.z, xcz = Rc.w;

    float x[8], y[8], z[8];
    x[0]=q0.x; y[0]=q0.y; z[0]=q0.z;
    x[1]=q0.w; y[1]=q1.x; z[1]=q1.y;
    x[2]=q1.z; y[2]=q1.w; z[2]=q2.x;
    x[3]=q2.y; y[3]=q2.z; z[3]=q2.w;
    x[4]=q3.x; y[4]=q3.y; z[4]=q3.z;
    x[5]=q3.w; y[5]=q4.x; z[5]=q4.y;
    x[6]=q4.z; y[6]=q4.w; z[6]=q5.x;
    x[7]=q5.y; y[7]=q5.z; z[7]=q5.w;

    float ox[8], oy[8], oz[8];
    #pragma unroll
    for (int j = 0; j < 8; j++) {
        float dx = x[j] - xcx, dy = y[j] - xcy, dz = z[j] - xcz;
        ox[j] = dx*R0 + dy*R3 + dz*R6;
        oy[j] = dx*R1 + dy*R4 + dz*R7;
        oz[j] = dx*R2 + dy*R5 + dz*R8;
    }

    float4* po = (float4*)(out + (size_t)f * (NATOMS * 3) + sub * 24);
    po[0] = make_float4(ox[0], oy[0], oz[0], ox[1]);
    po[1] = make_float4(oy[1], oz[1], ox[2], oy[2]);
    po[2] = make_float4(oz[2], ox[3], oy[3], oz[3]);
    po[3] = make_float4(ox[4], oy[4], oz[4], ox[5]);
    po[4] = make_float4(oy[5], oz[5], ox[6], oy[6]);
    po[5] = make_float4(oz[6], ox[7], oy[7], oz[7]);
}

// ============ Fallback: round-4 fused kernel (if workspace too small) ======
__global__ __launch_bounds__(512) void align_fused_kernel(
    const float* __restrict__ traj,
    const float* __restrict__ ref_pos,
    const int* __restrict__ align_idx,
    float* __restrict__ out,
    int B)
{
    __shared__ float4 s_rmap[NATOMS];
    __shared__ float s_cov[32][13];

    const int t   = threadIdx.x;
    const int f   = t >> 4;
    const int sub = t & 15;
    const int gf  = blockIdx.x * 32 + f;
    const bool valid = (gf < B);

    float x[8], y[8], z[8];
    if (valid) {
        const float4* p = (const float4*)(traj + (size_t)gf * (NATOMS * 3) + sub * 24);
        float4 q0 = p[0], q1 = p[1], q2 = p[2], q3 = p[3], q4 = p[4], q5 = p[5];
        x[0]=q0.x; y[0]=q0.y; z[0]=q0.z;
        x[1]=q0.w; y[1]=q1.x; z[1]=q1.y;
        x[2]=q1.z; y[2]=q1.w; z[2]=q2.x;
        x[3]=q2.y; y[3]=q2.z; z[3]=q2.w;
        x[4]=q3.x; y[4]=q3.y; z[4]=q3.z;
        x[5]=q3.w; y[5]=q4.x; z[5]=q4.y;
        x[6]=q4.z; y[6]=q4.w; z[6]=q5.x;
        x[7]=q5.y; y[7]=q5.z; z[7]=q5.w;
    } else {
        #pragma unroll
        for (int j = 0; j < 8; j++) { x[j]=0.f; y[j]=0.f; z[j]=0.f; }
    }

    if (t < NALIGN) {
        const float4 z4 = make_float4(0.f, 0.f, 0.f, 0.f);
        s_rmap[t]          = z4;
        s_rmap[t + NALIGN] = z4;
        int idx = align_idx[t];
        float rx = ref_pos[idx * 3 + 0];
        float ry = ref_pos[idx * 3 + 1];
        float rz = ref_pos[idx * 3 + 2];
        float sx = rx, sy = ry, sz = rz;
        #pragma unroll
        for (int off = 32; off >= 1; off >>= 1) {
            sx += __shfl_xor(sx, off);
            sy += __shfl_xor(sy, off);
            sz += __shfl_xor(sz, off);
        }
        const float inv = 1.0f / (float)NALIGN;
        int slot = ((idx & 7) << 4) | (idx >> 3);
        s_rmap[slot] = make_float4(rx - sx * inv, ry - sy * inv, rz - sz * inv, 1.0f);
    }
    __syncthreads();

    {
        float sx = 0.f, sy = 0.f, sz = 0.f;
        float c[9] = {0.f,0.f,0.f,0.f,0.f,0.f,0.f,0.f,0.f};
        #pragma unroll
        for (int j = 0; j < 8; j++) {
            float4 rm = s_rmap[(j << 4) | sub];
            sx += rm.w * x[j]; sy += rm.w * y[j]; sz += rm.w * z[j];
            c[0] += x[j]*rm.x; c[1] += x[j]*rm.y; c[2] += x[j]*rm.z;
            c[3] += y[j]*rm.x; c[4] += y[j]*rm.y; c[5] += y[j]*rm.z;
            c[6] += z[j]*rm.x; c[7] += z[j]*rm.y; c[8] += z[j]*rm.z;
        }
        #pragma unroll
        for (int off = 8; off >= 1; off >>= 1) {
            sx += __shfl_xor(sx, off);
            sy += __shfl_xor(sy, off);
            sz += __shfl_xor(sz, off);
            #pragma unroll
            for (int jj = 0; jj < 9; jj++) c[jj] += __shfl_xor(c[jj], off);
        }
        if (sub == 0) {
            #pragma unroll
            for (int jj = 0; jj < 9; jj++) s_cov[f][jj] = c[jj];
            const float inv = 1.0f / (float)NALIGN;
            s_cov[f][9]  = sx * inv;
            s_cov[f][10] = sy * inv;
            s_cov[f][11] = sz * inv;
        }
    }
    __syncthreads();

    if (t < 32) {
        float m[9];
        #pragma unroll
        for (int j = 0; j < 9; j++) m[j] = s_cov[t][j];
        float R[9];
        svd_rotation(m, R);
        #pragma unroll
        for (int j = 0; j < 9; j++) s_cov[t][j] = R[j];
    }
    __syncthreads();

    if (valid) {
        float R0 = s_cov[f][0], R1 = s_cov[f][1], R2 = s_cov[f][2];
        float R3 = s_cov[f][3], R4 = s_cov[f][4], R5 = s_cov[f][5];
        float R6 = s_cov[f][6], R7 = s_cov[f][7], R8 = s_cov[f][8];
        float xcx = s_cov[f][9], xcy = s_cov[f][10], xcz = s_cov[f][11];

        float ox[8], oy[8], oz[8];
        #pragma unroll
        for (int j = 0; j < 8; j++) {
            float dx = x[j] - xcx, dy = y[j] - xcy, dz = z[j] - xcz;
            ox[j] = dx*R0 + dy*R3 + dz*R6;
            oy[j] = dx*R1 + dy*R4 + dz*R7;
            oz[j] = dx*R2 + dy*R5 + dz*R8;
        }
        float4* po = (float4*)(out + (size_t)gf * (NATOMS * 3) + sub * 24);
        po[0] = make_float4(ox[0], oy[0], oz[0], ox[1]);
        po[1] = make_float4(oy[1], oz[1], ox[2], oy[2]);
        po[2] = make_float4(oz[2], ox[3], oy[3], oz[3]);
        po[3] = make_float4(ox[4], oy[4], oz[4], ox[5]);
        po[4] = make_float4(oy[5], oz[5], ox[6], oy[6]);
        po[5] = make_float4(oz[6], ox[7], oy[7], oz[7]);
    }
}

extern "C" void kernel_launch(void* const* d_in, const int* in_sizes, int n_in,
                              void* d_out, int out_size, void* d_ws, size_t ws_size,
                              hipStream_t stream) {
    const float* traj      = (const float*)d_in[0];
    const float* ref_pos   = (const float*)d_in[1];
    const int*   align_idx = (const int*)d_in[2];
    float*       out       = (float*)d_out;

    int B = in_sizes[0] / (NATOMS * 3);
    size_t need = (size_t)B * 12 * sizeof(float);

    if (d_ws != nullptr && ws_size >= need) {
        float* rmat = (float*)d_ws;
        int grid1 = (B + FPB1 - 1) / FPB1;
        cov_svd_kernel<<<grid1, TPB1, 0, stream>>>(traj, ref_pos, align_idx, rmat, B);
        long long threads2 = (long long)B * 16;
        int grid2 = (int)((threads2 + TPB2 - 1) / TPB2);
        apply_kernel<<<grid2, TPB2, 0, stream>>>(traj, rmat, out, B);
    } else {
        int grid = (B + 31) / 32;
        align_fused_kernel<<<grid, 512, 0, stream>>>(traj, ref_pos, align_idx, out, B);
    }
}

// Round 8
// 195.287 us; speedup vs baseline: 1.0744x; 1.0744x over previous
//
#include <hip/hip_runtime.h>
#include <math.h>

#define NATOMS 128
#define NALIGN 64
#define WPB    8                  // waves per block
#define FPW    2                  // frames per wave (2*384 floats = 192 float4)
#define FPB    (WPB * FPW)        // 16 frames per block
#define TPB    (WPB * 64)         // 512

// Branchless Jacobi rotation on symmetric 3x3 for pair (p,q); third index r.
// Tiny/zero apq degenerates to identity rotation via clamped denominator
// (tau -> +-huge -> t -> 0, c -> 1, s -> 0). NaN-free, divergence-free.
#define JACOBI_ROT(app, aqq, apq, arp, arq, pcol, qcol)                 \
  {                                                                     \
    float _apq = (apq);                                                 \
    float _den = 2.0f * _apq;                                           \
    _den = copysignf(fmaxf(fabsf(_den), 1e-30f), _den);                 \
    float _tau = ((aqq) - (app)) / _den;                                \
    float _t = (_tau >= 0.0f ? 1.0f : -1.0f) /                          \
               (fabsf(_tau) + sqrtf(1.0f + _tau * _tau));               \
    float _c = rsqrtf(1.0f + _t * _t);                                  \
    float _s = _t * _c;                                                 \
    (app) -= _t * _apq;                                                 \
    (aqq) += _t * _apq;                                                 \
    (apq) = 0.0f;                                                       \
    float _rp = (arp), _rq = (arq);                                     \
    (arp) = _c * _rp - _s * _rq;                                        \
    (arq) = _s * _rp + _c * _rq;                                        \
    _Pragma("unroll")                                                   \
    for (int _r = 0; _r < 3; _r++) {                                    \
      float _vp = v[3 * _r + (pcol)], _vq = v[3 * _r + (qcol)];         \
      v[3 * _r + (pcol)] = _c * _vp - _s * _vq;                         \
      v[3 * _r + (qcol)] = _s * _vp + _c * _vq;                         \
    }                                                                   \
  }

// SVD-based rotation: 3x3 m[9] (row-major) -> R(9). Branchless throughout.
__device__ __forceinline__ void svd_rotation(const float* m, float* R)
{
    float a00 = m[0]*m[0] + m[3]*m[3] + m[6]*m[6];
    float a01 = m[0]*m[1] + m[3]*m[4] + m[6]*m[7];
    float a02 = m[0]*m[2] + m[3]*m[5] + m[6]*m[8];
    float a11 = m[1]*m[1] + m[4]*m[4] + m[7]*m[7];
    float a12 = m[1]*m[2] + m[4]*m[5] + m[7]*m[8];
    float a22 = m[2]*m[2] + m[5]*m[5] + m[8]*m[8];

    float v[9] = {1.f,0.f,0.f, 0.f,1.f,0.f, 0.f,0.f,1.f};
    #pragma unroll
    for (int sweep = 0; sweep < 5; sweep++) {
        JACOBI_ROT(a00, a11, a01, a02, a12, 0, 1);
        JACOBI_ROT(a00, a22, a02, a01, a12, 0, 2);
        JACOBI_ROT(a11, a22, a12, a01, a02, 1, 2);
    }

    float dd[3] = {a00, a11, a22};
    #pragma unroll
    for (int pass = 0; pass < 3; pass++) {
        const int ii = (pass == 2) ? 1 : 0;   // 0,0,1
        const int jj = (pass == 0) ? 1 : 2;   // 1,2,2
        float di = dd[ii], dj = dd[jj];
        bool sw = di < dj;
        dd[ii] = sw ? dj : di;
        dd[jj] = sw ? di : dj;
        #pragma unroll
        for (int rr = 0; rr < 3; rr++) {
            float a = v[3*rr+ii], b = v[3*rr+jj];
            v[3*rr+ii] = sw ? b : a;
            v[3*rr+jj] = sw ? a : b;
        }
    }

    float v0x = v[0], v0y = v[3], v0z = v[6];
    float v1x = v[1], v1y = v[4], v1z = v[7];
    float v2x = v[2], v2y = v[5], v2z = v[8];

    float u1x = m[0]*v0x + m[1]*v0y + m[2]*v0z;
    float u1y = m[3]*v0x + m[4]*v0y + m[5]*v0z;
    float u1z = m[6]*v0x + m[7]*v0y + m[8]*v0z;
    float n1 = rsqrtf(fmaxf(u1x*u1x + u1y*u1y + u1z*u1z, 1e-30f));
    u1x *= n1; u1y *= n1; u1z *= n1;

    float u2x = m[0]*v1x + m[1]*v1y + m[2]*v1z;
    float u2y = m[3]*v1x + m[4]*v1y + m[5]*v1z;
    float u2z = m[6]*v1x + m[7]*v1y + m[8]*v1z;
    float d12 = u1x*u2x + u1y*u2y + u1z*u2z;
    u2x -= d12 * u1x; u2y -= d12 * u1y; u2z -= d12 * u1z;
    float n2 = rsqrtf(fmaxf(u2x*u2x + u2y*u2y + u2z*u2z, 1e-30f));
    u2x *= n2; u2y *= n2; u2z *= n2;

    float u3x = u1y*u2z - u1z*u2y;
    float u3y = u1z*u2x - u1x*u2z;
    float u3z = u1x*u2y - u1y*u2x;
    float cxv = v1y*v2z - v1z*v2y;
    float cyv = v1z*v2x - v1x*v2z;
    float czv = v1x*v2y - v1y*v2x;
    float detv = v0x*cxv + v0y*cyv + v0z*czv;
    float sg = (detv >= 0.f) ? 1.f : -1.f;
    u3x *= sg; u3y *= sg; u3z *= sg;

    R[0] = u1x*v0x + u2x*v1x + u3x*v2x;
    R[1] = u1x*v0y + u2x*v1y + u3x*v2y;
    R[2] = u1x*v0z + u2x*v1z + u3x*v2z;
    R[3] = u1y*v0x + u2y*v1x + u3y*v2x;
    R[4] = u1y*v0y + u2y*v1y + u3y*v2y;
    R[5] = u1y*v0z + u2y*v1z + u3y*v2z;
    R[6] = u1z*v0x + u2z*v1x + u3z*v2x;
    R[7] = u1z*v0y + u2z*v1y + u3z*v2y;
    R[8] = u1z*v0z + u2z*v1z + u3z*v2z;
}

// Byte address of owner-lane o's sub-slot so (so=0..2). The XOR only touches
// bits 4-5 (values 0/16/32/48), so the permutation stays INSIDE o's own 64B
// slot -> bijective by construction. Bank-group (addr bits 4-6) =
// ((o&1)<<2) | (((o>>1)&3) ^ so): for fixed so, lanes o=0..7 cover all 8
// groups -> 8 lanes/group = the b128 LDS floor.
__device__ __forceinline__ int slotAddr(int o, int so) {
    return (o << 6) | ((so << 4) ^ ((o & 6) << 3));
}

__global__ __launch_bounds__(TPB) void align_kernel(
    const float* __restrict__ traj,
    const float* __restrict__ ref_pos,
    const int* __restrict__ align_idx,
    float* __restrict__ out,
    int B)
{
    __shared__ float4 s_rmap[NATOMS];                      // one shared copy
    __shared__ __align__(16) float s_stage[WPB][1024];     // 4 KB per wave
    __shared__ float s_cov[FPB][13];                       // cov+xc -> R+xc

    const int t = threadIdx.x;
    const int w = t >> 6;          // wave 0..7
    const int l = t & 63;          // lane
    const int chunk0 = blockIdx.x * FPB + w * FPW;   // first frame of this wave
    const int lim = B * 96;        // total float4 count of traj

    const float4* __restrict__ gin = (const float4*)traj;
    char* wst = (char*)&s_stage[w][0];

    // ---------- stage-in: 3 perfectly-coalesced b128 loads per lane ----------
    float4 st[3];
    #pragma unroll
    for (int c = 0; c < 3; c++) {
        int gq = chunk0 * 96 + c * 64 + l;
        st[c] = (gq < lim) ? gin[gq] : make_float4(0.f, 0.f, 0.f, 0.f);
    }

    // ---------- wave 0: build the block-shared centered-ref inverse map ------
    if (t < NALIGN) {
        const float4 z4 = make_float4(0.f, 0.f, 0.f, 0.f);
        s_rmap[t]          = z4;
        s_rmap[t + NALIGN] = z4;
        int idx = align_idx[t];
        float rx = ref_pos[idx * 3 + 0];
        float ry = ref_pos[idx * 3 + 1];
        float rz = ref_pos[idx * 3 + 2];
        float sx = rx, sy = ry, sz = rz;
        #pragma unroll
        for (int off = 32; off >= 1; off >>= 1) {
            sx += __shfl_xor(sx, off);
            sy += __shfl_xor(sy, off);
            sz += __shfl_xor(sz, off);
        }
        const float inv = 1.0f / (float)NALIGN;
        int slot = ((idx & 3) << 5) | (idx >> 2);
        s_rmap[slot] = make_float4(rx - sx*inv, ry - sy*inv, rz - sz*inv, 1.0f);
    }

    // ---------- scatter staged float4s into swizzled atom slots ----------
    #pragma unroll
    for (int c = 0; c < 3; c++) {
        int q  = c * 64 + l;          // float4 index within the 2-frame chunk
        int o  = q / 3;               // owner lane (holds 4 atoms = 3 float4)
        int so = q - 3 * o;           // sub-slot 0..2
        *(float4*)(wst + slotAddr(o, so)) = st[c];
    }
    __syncthreads();   // B1: rmap + staged atoms visible

    // ---------- transpose read: this lane's 4 atoms (floor-conflict b128) ---
    float4 u0 = *(const float4*)(wst + slotAddr(l, 0));
    float4 u1 = *(const float4*)(wst + slotAddr(l, 1));
    float4 u2 = *(const float4*)(wst + slotAddr(l, 2));
    float x[4] = { u0.x, u0.w, u1.z, u2.y };
    float y[4] = { u0.y, u1.x, u1.w, u2.z };
    float z[4] = { u0.z, u1.y, u2.x, u2.w };

    // ---------- centroid + cross-covariance (sum(r)=0 trick) ----------
    const int lf = l & 31;            // lane within the frame's 32-group
    {
        float sx = 0.f, sy = 0.f, sz = 0.f;
        float c9[9] = {0.f,0.f,0.f,0.f,0.f,0.f,0.f,0.f,0.f};
        #pragma unroll
        for (int j = 0; j < 4; j++) {
            float4 rm = s_rmap[(j << 5) | lf];
            sx += rm.w * x[j]; sy += rm.w * y[j]; sz += rm.w * z[j];
            c9[0] += x[j]*rm.x; c9[1] += x[j]*rm.y; c9[2] += x[j]*rm.z;
            c9[3] += y[j]*rm.x; c9[4] += y[j]*rm.y; c9[5] += y[j]*rm.z;
            c9[6] += z[j]*rm.x; c9[7] += z[j]*rm.y; c9[8] += z[j]*rm.z;
        }
        #pragma unroll
        for (int off = 16; off >= 1; off >>= 1) {
            sx += __shfl_xor(sx, off);
            sy += __shfl_xor(sy, off);
            sz += __shfl_xor(sz, off);
            #pragma unroll
            for (int jj = 0; jj < 9; jj++) c9[jj] += __shfl_xor(c9[jj], off);
        }
        if (lf == 0) {
            int fi = w * FPW + (l >> 5);
            #pragma unroll
            for (int jj = 0; jj < 9; jj++) s_cov[fi][jj] = c9[jj];
            const float inv = 1.0f / (float)NALIGN;
            s_cov[fi][9]  = sx * inv;
            s_cov[fi][10] = sy * inv;
            s_cov[fi][11] = sz * inv;
        }
    }
    __syncthreads();   // B2: covariances visible

    // ---------- 16 lane-dense SVDs on a quarter of wave 0 ----------
    if (t < FPB && (blockIdx.x * FPB + t) < B) {
        float m[9];
        #pragma unroll
        for (int j = 0; j < 9; j++) m[j] = s_cov[t][j];
        float R[9];
        svd_rotation(m, R);
        #pragma unroll
        for (int j = 0; j < 9; j++) s_cov[t][j] = R[j];
    }
    __syncthreads();   // B3: rotations visible

    // ---------- rotate register-resident atoms, write back to own slot ------
    {
        const int fi = w * FPW + (l >> 5);
        float R0 = s_cov[fi][0], R1 = s_cov[fi][1], R2 = s_cov[fi][2];
        float R3 = s_cov[fi][3], R4 = s_cov[fi][4], R5 = s_cov[fi][5];
        float R6 = s_cov[fi][6], R7 = s_cov[fi][7], R8 = s_cov[fi][8];
        float xcx = s_cov[fi][9], xcy = s_cov[fi][10], xcz = s_cov[fi][11];

        float ox[4], oy[4], oz[4];
        #pragma unroll
        for (int j = 0; j < 4; j++) {
            float dx = x[j] - xcx, dy = y[j] - xcy, dz = z[j] - xcz;
            ox[j] = dx*R0 + dy*R3 + dz*R6;
            oy[j] = dx*R1 + dy*R4 + dz*R7;
            oz[j] = dx*R2 + dy*R5 + dz*R8;
        }

        *(float4*)(wst + slotAddr(l, 0)) = make_float4(ox[0], oy[0], oz[0], ox[1]);
        *(float4*)(wst + slotAddr(l, 1)) = make_float4(oy[1], oz[1], ox[2], oy[2]);
        *(float4*)(wst + slotAddr(l, 2)) = make_float4(oz[2], ox[3], oy[3], oz[3]);
    }
    __syncthreads();   // B4: rotated atoms visible

    // ---------- reverse transpose + 3 perfectly-coalesced b128 stores -------
    float4* __restrict__ gout = (float4*)out;
    #pragma unroll
    for (int c = 0; c < 3; c++) {
        int q  = c * 64 + l;
        int o  = q / 3;
        int so = q - 3 * o;
        float4 v4 = *(const float4*)(wst + slotAddr(o, so));
        int gq = chunk0 * 96 + q;
        if (gq < lim) gout[gq] = v4;
    }
}

extern "C" void kernel_launch(void* const* d_in, const int* in_sizes, int n_in,
                              void* d_out, int out_size, void* d_ws, size_t ws_size,
                              hipStream_t stream) {
    const float* traj      = (const float*)d_in[0];
    const float* ref_pos   = (const float*)d_in[1];
    const int*   align_idx = (const int*)d_in[2];
    float*       out       = (float*)d_out;

    int B = in_sizes[0] / (NATOMS * 3);
    int grid = (B + FPB - 1) / FPB;
    align_kernel<<<grid, TPB, 0, stream>>>(traj, ref_pos, align_idx, out, B);
}